// Round 13
// baseline (279.623 us; speedup 1.0000x reference)
//
#include <hip/hip_runtime.h>
#include <cmath>

// ---------------------------------------------------------------------------
// Causal MHA. B=4, T=2048, C=1024, NH=16, HD=64.
//   0) cast x -> bf16; transpose-cast w_qkv, w_out -> bf16 [N,K]
//   1) qkv = xb @ wqkvT^T via gemm256 (BM256xBN128, BK64, 4-phase, vmcnt(2),
//      st_16x32 swizzle, grid 768 = 3 rounds) + fused V-transpose epilogue.
//   2) flash attention v10: r7 structure with KT=128 staged keys per iter
//      (was 64) -> barrier+vmcnt(0)-drain count HALVES for the heavy tile
//      (32->16 rounds). LDS 64KB (2 blocks/CU = grid residency, no loss).
//      Same swizzle involution; per-sub causal guards handle overshoot.
//      Keep <=128 VGPR (r4 lesson).
//   3) out = ctxb @ woutT^T + b_out via gemm256 (grid 256 = 1 round).
// Noise note (r9/r10): totals carry +-3% container drift; judge changes by
// per-dispatch counters, not total alone.
// ---------------------------------------------------------------------------

typedef __bf16 bf16x4 __attribute__((ext_vector_type(4)));
typedef __bf16 bf16x8 __attribute__((ext_vector_type(8)));
typedef float  f32x4  __attribute__((ext_vector_type(4)));
typedef float  f32x16 __attribute__((ext_vector_type(16)));

__device__ __forceinline__ void gload_lds16(const __bf16* g, __bf16* l) {
    __builtin_amdgcn_global_load_lds(
        (const __attribute__((address_space(1))) void*)g,
        (__attribute__((address_space(3))) void*)l,
        16, 0, 0);
}

__device__ __forceinline__ unsigned packbf(float a, float b) {
    union { __bf16 h[2]; unsigned u; } t;
    t.h[0] = (__bf16)a; t.h[1] = (__bf16)b;
    return t.u;
}

// v_permlane32_swap_b32: a = [a.lo | b.lo], b = [a.hi | b.hi] (lane i <-> i+32)
__device__ __forceinline__ void permswap(unsigned& a, unsigned& b) {
    asm volatile("v_permlane32_swap_b32 %0, %1" : "+v"(a), "+v"(b));
}

#define BAR()  __builtin_amdgcn_s_barrier()
#define VM2()  { asm volatile("s_waitcnt vmcnt(2)" ::: "memory"); \
                 __builtin_amdgcn_sched_barrier(0); }

// ---- cast fp32 -> bf16, 4 elems/thread -------------------------------------
__global__ __launch_bounds__(256) void cast_bf16(const float* __restrict__ in,
                                                 __bf16* __restrict__ out, int n4) {
    int i = blockIdx.x * 256 + threadIdx.x;
    if (i >= n4) return;
    float4 f = *(const float4*)(in + (size_t)i * 4);
    bf16x4 o;
    o[0] = (__bf16)f.x; o[1] = (__bf16)f.y; o[2] = (__bf16)f.z; o[3] = (__bf16)f.w;
    *(bf16x4*)(out + (size_t)i * 4) = o;
}

// ---- transpose + cast: W[K,N] fp32 -> WT[N,K] bf16 -------------------------
__global__ __launch_bounds__(256) void transpose_cast(const float* __restrict__ W,
                                                      __bf16* __restrict__ WT,
                                                      int K, int N) {
    __shared__ float tile[32][33];
    const int n0 = blockIdx.x * 32, k0 = blockIdx.y * 32;
    const int tx = threadIdx.x & 31, ty = threadIdx.x >> 5;
    #pragma unroll
    for (int i = 0; i < 4; ++i)
        tile[ty + 8 * i][tx] = W[(size_t)(k0 + ty + 8 * i) * N + n0 + tx];
    __syncthreads();
    #pragma unroll
    for (int i = 0; i < 4; ++i)
        WT[(size_t)(n0 + ty + 8 * i) * K + k0 + tx] = (__bf16)tile[tx][ty + 8 * i];
}

// ---------------------------------------------------------------------------
// gemm256: C[M,N] = A[M,K] @ BT[N,K]^T. BM=256, BN=128, BK=64. 512 threads =
// 8 waves (4M x 2N), wave tile 64x64, acc[4][4], 16x16x32 MFMA. LDS 96 KiB.
// 4-phase schedule per K-tile; vmcnt(2) invariant (see r8). st_16x32 swizzle
// both-sides; grid must be %8==0 for the XCD swizzle.
// VOUT epilogue: for col>=2048 (V third), also store transposed 8B packs.
// ---------------------------------------------------------------------------
template <typename OutT, bool BIAS, bool VOUT>
__global__ __launch_bounds__(512) void gemm256(const __bf16* __restrict__ A,
                                               const __bf16* __restrict__ BT,
                                               OutT* __restrict__ Cc,
                                               const float* __restrict__ bias,
                                               __bf16* __restrict__ Vt,
                                               int M, int N, int K) {
    __shared__ __attribute__((aligned(16))) char lds[98304];
    const int tid = threadIdx.x, lane = tid & 63, w = tid >> 6;
    const int wr = w >> 1, wc = w & 1, cc = lane & 15, gg = lane >> 4;

    const int cpx = gridDim.x >> 3;
    const int swz = ((int)blockIdx.x & 7) * cpx + ((int)blockIdx.x >> 3);
    const int nbx = N >> 7;
    const int rowBase = (swz / nbx) << 8;
    const int colBase = (swz % nbx) << 7;
    const int NT = K >> 6;

    const int sChunk = (lane & 7) ^ (((lane >> 5) & 1) << 1);
    const int rsub   = lane >> 3;

    auto stA = [&](int t, int h) {
        const int buf = t & 1, k0 = (t % NT) * 64;
        #pragma unroll
        for (int l = 0; l < 2; ++l) {
            int idx   = l * 8 + w;
            int rbase = h * 128 + idx * 8;
            gload_lds16(A + (size_t)(rowBase + rbase + rsub) * K + k0 + sChunk * 8,
                        (__bf16*)(lds + buf * 32768 + rbase * 128 + lane * 16));
        }
    };
    auto stB = [&](int t) {
        const int buf = t & 1, k0 = (t % NT) * 64;
        #pragma unroll
        for (int l = 0; l < 2; ++l) {
            int idx   = l * 8 + w;
            int rbase = idx * 8;
            gload_lds16(BT + (size_t)(colBase + rbase + rsub) * K + k0 + sChunk * 8,
                        (__bf16*)(lds + 65536 + buf * 16384 + rbase * 128 + lane * 16));
        }
    };

    f32x4 acc[4][4];
    #pragma unroll
    for (int i = 0; i < 4; ++i)
        #pragma unroll
        for (int j = 0; j < 4; ++j) acc[i][j] = f32x4{0.f, 0.f, 0.f, 0.f};
    bf16x8 afr[4], bfr[8];

    auto rdA = [&](int buf, int mh) {
        const char* base = lds + buf * 32768;
        #pragma unroll
        for (int i = 0; i < 2; ++i)
            #pragma unroll
            for (int kk = 0; kk < 2; ++kk) {
                int r  = wr * 64 + mh * 32 + i * 16 + cc;
                int cb = (kk * 64 + gg * 16) ^ (((cc >> 2) & 1) << 5);
                afr[i * 2 + kk] = *(const bf16x8*)(base + r * 128 + cb);
            }
    };
    auto rdB = [&](int buf) {
        const char* base = lds + 65536 + buf * 16384;
        #pragma unroll
        for (int j = 0; j < 4; ++j)
            #pragma unroll
            for (int kk = 0; kk < 2; ++kk) {
                int r  = wc * 64 + j * 16 + cc;
                int cb = (kk * 64 + gg * 16) ^ (((cc >> 2) & 1) << 5);
                bfr[j * 2 + kk] = *(const bf16x8*)(base + r * 128 + cb);
            }
    };

#define QMFMA(MH, NH)                                                        \
    _Pragma("unroll") for (int i = 0; i < 2; ++i)                            \
    _Pragma("unroll") for (int j = 0; j < 2; ++j)                            \
    _Pragma("unroll") for (int kk = 0; kk < 2; ++kk)                         \
        acc[(MH)*2 + i][(NH)*2 + j] = __builtin_amdgcn_mfma_f32_16x16x32_bf16( \
            afr[i*2 + kk], bfr[((NH)*2 + j)*2 + kk], acc[(MH)*2 + i][(NH)*2 + j], 0, 0, 0);

    stA(0, 0); stB(0); stA(0, 1); stB(1);
    VM2(); BAR();

    for (int t = 0; t < NT; ++t) {
        const int buf = t & 1;
        rdA(buf, 0); rdB(buf);
        stA(t + 1, 0);
        BAR();
        __builtin_amdgcn_s_setprio(1); QMFMA(0, 0); __builtin_amdgcn_s_setprio(0);
        BAR();
        stA(t + 1, 1);
        BAR();
        __builtin_amdgcn_s_setprio(1); QMFMA(0, 1); __builtin_amdgcn_s_setprio(0);
        BAR();
        rdA(buf, 1);
        stB(t + 2);
        BAR();
        __builtin_amdgcn_s_setprio(1); QMFMA(1, 0); __builtin_amdgcn_s_setprio(0);
        BAR();
        BAR();
        __builtin_amdgcn_s_setprio(1); QMFMA(1, 1); __builtin_amdgcn_s_setprio(0);
        VM2(); BAR();
    }
#undef QMFMA

    #pragma unroll
    for (int i = 0; i < 4; ++i)
        #pragma unroll
        for (int j = 0; j < 4; ++j) {
            const int col = colBase + wc * 64 + j * 16 + cc;
            #pragma unroll
            for (int rr = 0; rr < 4; ++rr) {
                const int row = rowBase + wr * 64 + i * 16 + gg * 4 + rr;
                float v = acc[i][j][rr];
                if (BIAS) v += bias[col];
                Cc[(size_t)row * N + col] = (OutT)v;
            }
            if (VOUT && col >= 2048) {
                const int bh16 = ((rowBase >> 11) << 4) + ((col - 2048) >> 6);
                const int d    = (col - 2048) & 63;
                const int t0   = (rowBase & 2047) + wr * 64 + i * 16 + gg * 4;
                union { bf16x4 v4; uint2 u; } pk;
                #pragma unroll
                for (int rr = 0; rr < 4; ++rr) pk.v4[rr] = (__bf16)acc[i][j][rr];
                *(uint2*)(Vt + ((size_t)bh16 * 64 + d) * 2048 + t0) = pk.u;
            }
        }
}

// ---------------------------------------------------------------------------
// MFMA flash attention v10: pair-fused causal blocks, T12 in-register P,
// dbuf K/V via global_load_lds with KT=128 keys per staged tile (r13: halves
// barrier + vmcnt(0)-drain rounds for the heavy tile, 32->16). LDS 64KB ->
// LDS-capped 2 blocks/CU == grid residency. Swizzle involution unchanged:
// src chunk ^= row&7 (linear dest), read byte ^= (row&7)<<4. Per-sub causal
// guards (kb > srow+31 -> skip) handle the wider tile.
// S^T = mfma(K_frag, Q_frag): col = q = lane&31,
//       row = key = (r&3) + 8*(r>>2) + 4*(lane>>5)   [guide m74/m101]
// ---------------------------------------------------------------------------
__global__ __launch_bounds__(256) void flash_attn_mfma(const __bf16* __restrict__ qkv,
                                                       const __bf16* __restrict__ Vt,
                                                       __bf16* __restrict__ ctx) {
    constexpr int T = 2048, C = 1024, HD = 64;
    constexpr int R3C = 3 * C;
    constexpr float K1 = 0.125f * 1.44269504088896f;   // scale * log2e
    constexpr float K2 = -16.0f * 1.44269504088896f;   // -M0 * log2e

    const int tid  = threadIdx.x;
    const int lane = tid & 63;
    const int w    = tid >> 6;
    const int q5   = lane & 31;
    const int half = lane >> 5;

    const int bh   = blockIdx.x;               // 0..63
    const int y    = blockIdx.y;               // 0..7
    const int qtA  = 15 - y;                   // heavy tile
    const int qtB  = y;                        // light tile (rides free)
    const int b    = bh >> 4;
    const int h    = bh & 15;
    const int srowA = qtA * 128 + w * 32;
    const int srowB = qtB * 128 + w * 32;
    const int nIter = qtA + 1;                 // 128-key tiles

    // double-buffered K/V: K [128][64] (128B rows), V^T [64][128] (256B rows)
    __shared__ __attribute__((aligned(16))) __bf16 KsL[2][128][64];
    __shared__ __attribute__((aligned(16))) __bf16 VsL[2][64][128];

    const __bf16* QrowA = qkv + (size_t)(b * T + srowA + q5) * R3C + h * HD;
    const __bf16* QrowB = qkv + (size_t)(b * T + srowB + q5) * R3C + h * HD;
    bf16x8 QbA[4], QbB[4];
    #pragma unroll
    for (int ks = 0; ks < 4; ++ks) {
        QbA[ks] = *(const bf16x8*)(QrowA + ks * 16 + half * 8);
        QbB[ks] = *(const bf16x8*)(QrowB + ks * 16 + half * 8);
    }

    f32x16 OA[2], OB[2];
    #pragma unroll
    for (int mb = 0; mb < 2; ++mb)
        #pragma unroll
        for (int r = 0; r < 16; ++r) { OA[mb][r] = 0.f; OB[mb][r] = 0.f; }
    float lsumA = 0.f, lsumB = 0.f;

    const __bf16* Kb  = qkv + (size_t)(b * T) * R3C + C + h * HD;
    const __bf16* Vtb = Vt + (size_t)bh * 64 * T;

    // stage one 128-key tile (8 gload_lds16/thread)
    auto stage = [&](int bufi, int kt) {
        #pragma unroll
        for (int i = 0; i < 4; ++i) {
            int idx = tid + 256 * i;
            int kr  = idx >> 3;                 // key row 0..127
            int c8  = idx & 7;                  // dest 16B chunk (hd/8)
            int cs  = c8 ^ (kr & 7);            // inverse-swizzled src chunk
            gload_lds16(Kb + (size_t)(kt + kr) * R3C + cs * 8,
                        &KsL[bufi][kr][c8 * 8]);
        }
        #pragma unroll
        for (int i = 0; i < 4; ++i) {
            int idx = tid + 256 * i;
            int d   = idx >> 4;                 // hd row 0..63
            int k16 = idx & 15;                 // dest 16B chunk (key/8)
            int ks_ = k16 ^ (d & 7);            // inverse-swizzled src chunk
            gload_lds16(Vtb + (size_t)d * T + kt + ks_ * 8,
                        &VsL[bufi][d][k16 * 8]);
        }
    };

    stage(0, 0);
    __syncthreads();

    for (int it = 0; it < nIter; ++it) {
        const int kt  = it * 128;
        const int cur = it & 1;
        if (it + 1 < nIter) stage(cur ^ 1, kt + 128);   // stage FIRST (r7)

        const char* kbase = (const char*)KsL[cur];
        const char* vbase = (const char*)VsL[cur];

        // one 32-key sub-tile (sub 0..3): S -> mask -> exp -> T12 pack -> PV
        auto subtile = [&](int sub, const bf16x8* Qb, int srow, f32x16* O, float& lsum) {
            const int kb = kt + sub * 32;
            f32x16 S;
            #pragma unroll
            for (int r = 0; r < 16; ++r) S[r] = 0.f;
            const int krow = sub * 32 + q5;
            const int kxor = (krow & 7) << 4;
            #pragma unroll
            for (int ks = 0; ks < 4; ++ks) {
                bf16x8 kf = *(const bf16x8*)(kbase + krow * 128 +
                                             (((ks * 16 + half * 8) * 2) ^ kxor));
                S = __builtin_amdgcn_mfma_f32_32x32x16_bf16(kf, Qb[ks], S, 0, 0, 0);
            }
            if (kb + 31 > srow) {
                #pragma unroll
                for (int r = 0; r < 16; ++r) {
                    int key = kb + (r & 3) + 8 * (r >> 2) + 4 * half;
                    if (key > srow + q5) S[r] = -1e30f;
                }
            }
            float p[16];
            #pragma unroll
            for (int r = 0; r < 16; ++r) {
                p[r] = exp2f(fmaf(S[r], K1, K2));
                lsum += p[r];
            }
            unsigned w0 = packbf(p[0],  p[1]);
            unsigned w1 = packbf(p[2],  p[3]);
            unsigned w2 = packbf(p[4],  p[5]);
            unsigned w3 = packbf(p[6],  p[7]);
            permswap(w0, w2);
            permswap(w1, w3);
            unsigned w4 = packbf(p[8],  p[9]);
            unsigned w5 = packbf(p[10], p[11]);
            unsigned w6 = packbf(p[12], p[13]);
            unsigned w7 = packbf(p[14], p[15]);
            permswap(w4, w6);
            permswap(w5, w7);
            union { unsigned u[4]; bf16x8 v; } pf0, pf1;
            pf0.u[0] = w0; pf0.u[1] = w1; pf0.u[2] = w2; pf0.u[3] = w3;
            pf1.u[0] = w4; pf1.u[1] = w5; pf1.u[2] = w6; pf1.u[3] = w7;
            const int vc = sub * 32 + half * 8;          // key offset in row
            #pragma unroll
            for (int mb = 0; mb < 2; ++mb) {
                const int vrow = mb * 32 + q5;
                const int vxor = (vrow & 7) << 4;
                bf16x8 v0 = *(const bf16x8*)(vbase + vrow * 256 + ((vc * 2) ^ vxor));
                O[mb] = __builtin_amdgcn_mfma_f32_32x32x16_bf16(v0, pf0.v, O[mb], 0, 0, 0);
                bf16x8 v1 = *(const bf16x8*)(vbase + vrow * 256 + (((vc + 16) * 2) ^ vxor));
                O[mb] = __builtin_amdgcn_mfma_f32_32x32x16_bf16(v1, pf1.v, O[mb], 0, 0, 0);
            }
        };

        #pragma unroll
        for (int sub = 0; sub < 4; ++sub)
            if (kt + sub * 32 <= srowA + 31)
                subtile(sub, QbA, srowA, OA, lsumA);
        #pragma unroll
        for (int sub = 0; sub < 4; ++sub)
            if (kt + sub * 32 <= srowB + 31)
                subtile(sub, QbB, srowB, OB, lsumB);

        __syncthreads();
    }

    const float invA = 1.f / (lsumA + __shfl_xor(lsumA, 32));
    const float invB = 1.f / (lsumB + __shfl_xor(lsumB, 32));

    __bf16* crowA = ctx + (size_t)(b * T + srowA + q5) * C + h * HD;
    __bf16* crowB = ctx + (size_t)(b * T + srowB + q5) * C + h * HD;
    #pragma unroll
    for (int mb = 0; mb < 2; ++mb)
        #pragma unroll
        for (int a = 0; a < 4; ++a) {
            union { bf16x4 v; uint2 u; } pA, pB;
            #pragma unroll
            for (int bq = 0; bq < 4; ++bq) {
                pA.v[bq] = (__bf16)(OA[mb][4 * a + bq] * invA);
                pB.v[bq] = (__bf16)(OB[mb][4 * a + bq] * invB);
            }
            *(uint2*)(crowA + mb * 32 + 8 * a + 4 * half) = pA.u;
            *(uint2*)(crowB + mb * 32 + 8 * a + 4 * half) = pB.u;
        }
}

extern "C" void kernel_launch(void* const* d_in, const int* in_sizes, int n_in,
                              void* d_out, int out_size, void* d_ws, size_t ws_size,
                              hipStream_t stream) {
    constexpr int B = 4, T = 2048, C = 1024;
    constexpr int M = B * T;          // 8192

    const float* x     = (const float*)d_in[0];
    const float* w_qkv = (const float*)d_in[1];
    const float* w_out = (const float*)d_in[2];
    const float* b_out = (const float*)d_in[3];
    float* out = (float*)d_out;

    char* ws = (char*)d_ws;
    __bf16* xb     = (__bf16*)(ws);                      // 16 MB
    __bf16* wqkvT  = (__bf16*)(ws + (16ull << 20));      //  6 MB
    __bf16* woutT  = (__bf16*)(ws + (22ull << 20));      //  2 MB
    __bf16* qkvb   = (__bf16*)(ws + (24ull << 20));      // 48 MB
    __bf16* ctxb   = (__bf16*)(ws + (72ull << 20));      // 16 MB
    __bf16* Vt     = (__bf16*)(ws + (88ull << 20));      // 16 MB

    // 0) casts / transposes
    cast_bf16<<<(M * C / 4 + 255) / 256, 256, 0, stream>>>(x, xb, M * C / 4);
    transpose_cast<<<dim3(3 * C / 32, C / 32), 256, 0, stream>>>(w_qkv, wqkvT, C, 3 * C);
    transpose_cast<<<dim3(C / 32, C / 32), 256, 0, stream>>>(w_out, woutT, C, C);

    // 1) qkv = xb @ wqkvT^T (bf16 out) + fused V-transpose into Vt
    gemm256<__bf16, false, true><<<768, 512, 0, stream>>>(
        xb, wqkvT, qkvb, nullptr, Vt, M, 3 * C, C);

    // 2) MFMA flash attention -> ctxb (KT=128 dbuf staging)
    flash_attn_mfma<<<dim3(B * 16, 8), 256, 0, stream>>>(qkvb, Vt, ctxb);

    // 3) out = ctxb @ woutT^T + b_out (fp32 out) -- gemm256, 256 blocks
    gemm256<float, true, false><<<256, 512, 0, stream>>>(
        ctxb, woutT, out, b_out, nullptr, M, C, C);
}

// Round 14
// 273.384 us; speedup vs baseline: 1.0228x; 1.0228x over previous
//
#include <hip/hip_runtime.h>
#include <cmath>

// ---------------------------------------------------------------------------
// Causal MHA. B=4, T=2048, C=1024, NH=16, HD=64.
//   0) cast x -> bf16; transpose-cast w_qkv, w_out -> bf16 [N,K].
//      r14: w_qkv Q-columns (n<1024) pre-scaled by K1=0.125*log2e, so flash's
//      softmax needs exp2f(S) only (fmaf deleted; the -16*log2e offset is a
//      constant factor on every p and cancels in O/lsum normalization).
//   1) qkv = xb @ wqkvT^T via gemm256 (BM256xBN128, BK64, 4-phase, vmcnt(2),
//      st_16x32 swizzle, grid 768 = 3 rounds) + fused V-transpose epilogue.
//   2) flash attention v11 = r7/r8 structure (KT=64, stage-first; r13's
//      KT=128 hurt: 97->103, VALU up -- barrier count was not the cost;
//      flash is VALU-issue-bound on softmax arithmetic) + exp2f(S) direct
//      + tree-reassociated lsum (4-deep, same op count, no new live regs).
//   3) out = ctxb @ woutT^T + b_out via gemm256 (grid 256 = 1 round).
// Keep flash <=128 VGPR (r4). Conflicts 4456448 = structural, accepted.
// ---------------------------------------------------------------------------

typedef __bf16 bf16x4 __attribute__((ext_vector_type(4)));
typedef __bf16 bf16x8 __attribute__((ext_vector_type(8)));
typedef float  f32x4  __attribute__((ext_vector_type(4)));
typedef float  f32x16 __attribute__((ext_vector_type(16)));

__device__ __forceinline__ void gload_lds16(const __bf16* g, __bf16* l) {
    __builtin_amdgcn_global_load_lds(
        (const __attribute__((address_space(1))) void*)g,
        (__attribute__((address_space(3))) void*)l,
        16, 0, 0);
}

__device__ __forceinline__ unsigned packbf(float a, float b) {
    union { __bf16 h[2]; unsigned u; } t;
    t.h[0] = (__bf16)a; t.h[1] = (__bf16)b;
    return t.u;
}

// v_permlane32_swap_b32: a = [a.lo | b.lo], b = [a.hi | b.hi] (lane i <-> i+32)
__device__ __forceinline__ void permswap(unsigned& a, unsigned& b) {
    asm volatile("v_permlane32_swap_b32 %0, %1" : "+v"(a), "+v"(b));
}

#define BAR()  __builtin_amdgcn_s_barrier()
#define VM2()  { asm volatile("s_waitcnt vmcnt(2)" ::: "memory"); \
                 __builtin_amdgcn_sched_barrier(0); }

// ---- cast fp32 -> bf16, 4 elems/thread -------------------------------------
__global__ __launch_bounds__(256) void cast_bf16(const float* __restrict__ in,
                                                 __bf16* __restrict__ out, int n4) {
    int i = blockIdx.x * 256 + threadIdx.x;
    if (i >= n4) return;
    float4 f = *(const float4*)(in + (size_t)i * 4);
    bf16x4 o;
    o[0] = (__bf16)f.x; o[1] = (__bf16)f.y; o[2] = (__bf16)f.z; o[3] = (__bf16)f.w;
    *(bf16x4*)(out + (size_t)i * 4) = o;
}

// ---- transpose + cast: W[K,N] fp32 -> WT[N,K] bf16; cols n<nScaleLim get
// *scale (r14: folds softmax scale*log2e into w_qkv's Q columns) -----------
__global__ __launch_bounds__(256) void transpose_cast(const float* __restrict__ W,
                                                      __bf16* __restrict__ WT,
                                                      int K, int N,
                                                      int nScaleLim, float scale) {
    __shared__ float tile[32][33];
    const int n0 = blockIdx.x * 32, k0 = blockIdx.y * 32;
    const int tx = threadIdx.x & 31, ty = threadIdx.x >> 5;
    #pragma unroll
    for (int i = 0; i < 4; ++i)
        tile[ty + 8 * i][tx] = W[(size_t)(k0 + ty + 8 * i) * N + n0 + tx];
    __syncthreads();
    #pragma unroll
    for (int i = 0; i < 4; ++i) {
        const int n = n0 + ty + 8 * i;
        float v = tile[tx][ty + 8 * i];
        if (n < nScaleLim) v *= scale;
        WT[(size_t)n * K + k0 + tx] = (__bf16)v;
    }
}

// ---------------------------------------------------------------------------
// gemm256: C[M,N] = A[M,K] @ BT[N,K]^T. BM=256, BN=128, BK=64. 512 threads =
// 8 waves (4M x 2N), wave tile 64x64, acc[4][4], 16x16x32 MFMA. LDS 96 KiB.
// 4-phase schedule per K-tile; vmcnt(2) invariant (see r8). st_16x32 swizzle
// both-sides; grid must be %8==0 for the XCD swizzle.
// VOUT epilogue: for col>=2048 (V third), also store transposed 8B packs.
// ---------------------------------------------------------------------------
template <typename OutT, bool BIAS, bool VOUT>
__global__ __launch_bounds__(512) void gemm256(const __bf16* __restrict__ A,
                                               const __bf16* __restrict__ BT,
                                               OutT* __restrict__ Cc,
                                               const float* __restrict__ bias,
                                               __bf16* __restrict__ Vt,
                                               int M, int N, int K) {
    __shared__ __attribute__((aligned(16))) char lds[98304];
    const int tid = threadIdx.x, lane = tid & 63, w = tid >> 6;
    const int wr = w >> 1, wc = w & 1, cc = lane & 15, gg = lane >> 4;

    const int cpx = gridDim.x >> 3;
    const int swz = ((int)blockIdx.x & 7) * cpx + ((int)blockIdx.x >> 3);
    const int nbx = N >> 7;
    const int rowBase = (swz / nbx) << 8;
    const int colBase = (swz % nbx) << 7;
    const int NT = K >> 6;

    const int sChunk = (lane & 7) ^ (((lane >> 5) & 1) << 1);
    const int rsub   = lane >> 3;

    auto stA = [&](int t, int h) {
        const int buf = t & 1, k0 = (t % NT) * 64;
        #pragma unroll
        for (int l = 0; l < 2; ++l) {
            int idx   = l * 8 + w;
            int rbase = h * 128 + idx * 8;
            gload_lds16(A + (size_t)(rowBase + rbase + rsub) * K + k0 + sChunk * 8,
                        (__bf16*)(lds + buf * 32768 + rbase * 128 + lane * 16));
        }
    };
    auto stB = [&](int t) {
        const int buf = t & 1, k0 = (t % NT) * 64;
        #pragma unroll
        for (int l = 0; l < 2; ++l) {
            int idx   = l * 8 + w;
            int rbase = idx * 8;
            gload_lds16(BT + (size_t)(colBase + rbase + rsub) * K + k0 + sChunk * 8,
                        (__bf16*)(lds + 65536 + buf * 16384 + rbase * 128 + lane * 16));
        }
    };

    f32x4 acc[4][4];
    #pragma unroll
    for (int i = 0; i < 4; ++i)
        #pragma unroll
        for (int j = 0; j < 4; ++j) acc[i][j] = f32x4{0.f, 0.f, 0.f, 0.f};
    bf16x8 afr[4], bfr[8];

    auto rdA = [&](int buf, int mh) {
        const char* base = lds + buf * 32768;
        #pragma unroll
        for (int i = 0; i < 2; ++i)
            #pragma unroll
            for (int kk = 0; kk < 2; ++kk) {
                int r  = wr * 64 + mh * 32 + i * 16 + cc;
                int cb = (kk * 64 + gg * 16) ^ (((cc >> 2) & 1) << 5);
                afr[i * 2 + kk] = *(const bf16x8*)(base + r * 128 + cb);
            }
    };
    auto rdB = [&](int buf) {
        const char* base = lds + 65536 + buf * 16384;
        #pragma unroll
        for (int j = 0; j < 4; ++j)
            #pragma unroll
            for (int kk = 0; kk < 2; ++kk) {
                int r  = wc * 64 + j * 16 + cc;
                int cb = (kk * 64 + gg * 16) ^ (((cc >> 2) & 1) << 5);
                bfr[j * 2 + kk] = *(const bf16x8*)(base + r * 128 + cb);
            }
    };

#define QMFMA(MH, NH)                                                        \
    _Pragma("unroll") for (int i = 0; i < 2; ++i)                            \
    _Pragma("unroll") for (int j = 0; j < 2; ++j)                            \
    _Pragma("unroll") for (int kk = 0; kk < 2; ++kk)                         \
        acc[(MH)*2 + i][(NH)*2 + j] = __builtin_amdgcn_mfma_f32_16x16x32_bf16( \
            afr[i*2 + kk], bfr[((NH)*2 + j)*2 + kk], acc[(MH)*2 + i][(NH)*2 + j], 0, 0, 0);

    stA(0, 0); stB(0); stA(0, 1); stB(1);
    VM2(); BAR();

    for (int t = 0; t < NT; ++t) {
        const int buf = t & 1;
        rdA(buf, 0); rdB(buf);
        stA(t + 1, 0);
        BAR();
        __builtin_amdgcn_s_setprio(1); QMFMA(0, 0); __builtin_amdgcn_s_setprio(0);
        BAR();
        stA(t + 1, 1);
        BAR();
        __builtin_amdgcn_s_setprio(1); QMFMA(0, 1); __builtin_amdgcn_s_setprio(0);
        BAR();
        rdA(buf, 1);
        stB(t + 2);
        BAR();
        __builtin_amdgcn_s_setprio(1); QMFMA(1, 0); __builtin_amdgcn_s_setprio(0);
        BAR();
        BAR();
        __builtin_amdgcn_s_setprio(1); QMFMA(1, 1); __builtin_amdgcn_s_setprio(0);
        VM2(); BAR();
    }
#undef QMFMA

    #pragma unroll
    for (int i = 0; i < 4; ++i)
        #pragma unroll
        for (int j = 0; j < 4; ++j) {
            const int col = colBase + wc * 64 + j * 16 + cc;
            #pragma unroll
            for (int rr = 0; rr < 4; ++rr) {
                const int row = rowBase + wr * 64 + i * 16 + gg * 4 + rr;
                float v = acc[i][j][rr];
                if (BIAS) v += bias[col];
                Cc[(size_t)row * N + col] = (OutT)v;
            }
            if (VOUT && col >= 2048) {
                const int bh16 = ((rowBase >> 11) << 4) + ((col - 2048) >> 6);
                const int d    = (col - 2048) & 63;
                const int t0   = (rowBase & 2047) + wr * 64 + i * 16 + gg * 4;
                union { bf16x4 v4; uint2 u; } pk;
                #pragma unroll
                for (int rr = 0; rr < 4; ++rr) pk.v4[rr] = (__bf16)acc[i][j][rr];
                *(uint2*)(Vt + ((size_t)bh16 * 64 + d) * 2048 + t0) = pk.u;
            }
        }
}

// ---------------------------------------------------------------------------
// MFMA flash attention v11 (r7/r8 structure): pair-fused causal blocks, T12
// in-register P, dbuf K/V (KT=64) via global_load_lds, stage at TOP of iter.
// r14: Q pre-scaled in weights -> p = exp2f(S) directly (no fmaf, no K2 --
// the constant factor cancels in O/lsum). lsum tree-reassociated (4-deep).
// Involution swizzle: src chunk ^= row&7 (linear dest), read ^= (row&7)<<4.
// S^T = mfma(K_frag, Q_frag): col = q = lane&31,
//       row = key = (r&3) + 8*(r>>2) + 4*(lane>>5)   [guide m74/m101]
// ---------------------------------------------------------------------------
__global__ __launch_bounds__(256) void flash_attn_mfma(const __bf16* __restrict__ qkv,
                                                       const __bf16* __restrict__ Vt,
                                                       __bf16* __restrict__ ctx) {
    constexpr int T = 2048, C = 1024, HD = 64;
    constexpr int R3C = 3 * C;

    const int tid  = threadIdx.x;
    const int lane = tid & 63;
    const int w    = tid >> 6;
    const int q5   = lane & 31;
    const int half = lane >> 5;

    const int bh   = blockIdx.x;               // 0..63
    const int y    = blockIdx.y;               // 0..7
    const int qtA  = 15 - y;                   // heavy tile
    const int qtB  = y;                        // light tile (rides free)
    const int b    = bh >> 4;
    const int h    = bh & 15;
    const int srowA = qtA * 128 + w * 32;
    const int srowB = qtB * 128 + w * 32;
    const int ktmaxA = qtA * 128 + 64;
    const int ktmaxB = qtB * 128 + 64;

    __shared__ __attribute__((aligned(16))) __bf16 KsL[2][64][64];
    __shared__ __attribute__((aligned(16))) __bf16 VsL[2][64][64];

    const __bf16* QrowA = qkv + (size_t)(b * T + srowA + q5) * R3C + h * HD;
    const __bf16* QrowB = qkv + (size_t)(b * T + srowB + q5) * R3C + h * HD;
    bf16x8 QbA[4], QbB[4];
    #pragma unroll
    for (int ks = 0; ks < 4; ++ks) {
        QbA[ks] = *(const bf16x8*)(QrowA + ks * 16 + half * 8);
        QbB[ks] = *(const bf16x8*)(QrowB + ks * 16 + half * 8);
    }

    f32x16 OA[2], OB[2];
    #pragma unroll
    for (int mb = 0; mb < 2; ++mb)
        #pragma unroll
        for (int r = 0; r < 16; ++r) { OA[mb][r] = 0.f; OB[mb][r] = 0.f; }
    float lsumA = 0.f, lsumB = 0.f;

    const __bf16* Kb  = qkv + (size_t)(b * T) * R3C + C + h * HD;
    const __bf16* Vtb = Vt + (size_t)bh * 64 * T;

    auto stage = [&](int bufi, int kt) {
        #pragma unroll
        for (int i = 0; i < 2; ++i) {
            int idx = tid + 256 * i;
            int kr  = idx >> 3;
            int c8  = idx & 7;
            int cs  = c8 ^ (kr & 7);
            gload_lds16(Kb + (size_t)(kt + kr) * R3C + cs * 8,
                        &KsL[bufi][kr][c8 * 8]);
        }
        #pragma unroll
        for (int i = 0; i < 2; ++i) {
            int idx = tid + 256 * i;
            int d   = idx >> 3;
            int k8  = idx & 7;
            int ks_ = k8 ^ (d & 7);
            gload_lds16(Vtb + (size_t)d * T + kt + ks_ * 8,
                        &VsL[bufi][d][k8 * 8]);
        }
    };

    stage(0, 0);
    __syncthreads();

    for (int kt = 0; kt <= ktmaxA; kt += 64) {
        const int cur = (kt >> 6) & 1;
        if (kt + 64 <= ktmaxA) stage(cur ^ 1, kt + 64);   // stage FIRST (r7)

        const char* kbase = (const char*)KsL[cur];
        const char* vbase = (const char*)VsL[cur];

        auto subtile = [&](int sub, const bf16x8* Qb, int srow, f32x16* O, float& lsum) {
            f32x16 S;
            #pragma unroll
            for (int r = 0; r < 16; ++r) S[r] = 0.f;
            const int krow = sub * 32 + q5;
            const int kxor = (krow & 7) << 4;
            #pragma unroll
            for (int ks = 0; ks < 4; ++ks) {
                bf16x8 kb = *(const bf16x8*)(kbase + krow * 128 +
                                             (((ks * 16 + half * 8) * 2) ^ kxor));
                S = __builtin_amdgcn_mfma_f32_32x32x16_bf16(kb, Qb[ks], S, 0, 0, 0);
            }
            if (kt + sub * 32 + 31 > srow) {
                #pragma unroll
                for (int r = 0; r < 16; ++r) {
                    int key = kt + sub * 32 + (r & 3) + 8 * (r >> 2) + 4 * half;
                    if (key > srow + q5) S[r] = -1e30f;
                }
            }
            // Q pre-scaled by 0.125*log2e in weights -> p = exp2(S) directly
            float p[16];
            #pragma unroll
            for (int r = 0; r < 16; ++r) p[r] = exp2f(S[r]);
            {   // tree lsum (4-deep, same op count, no long serial chain)
                float a0 = (p[0] + p[1]) + (p[2] + p[3]);
                float a1 = (p[4] + p[5]) + (p[6] + p[7]);
                float a2 = (p[8] + p[9]) + (p[10] + p[11]);
                float a3 = (p[12] + p[13]) + (p[14] + p[15]);
                lsum += (a0 + a1) + (a2 + a3);
            }
            unsigned w0 = packbf(p[0],  p[1]);
            unsigned w1 = packbf(p[2],  p[3]);
            unsigned w2 = packbf(p[4],  p[5]);
            unsigned w3 = packbf(p[6],  p[7]);
            permswap(w0, w2);
            permswap(w1, w3);
            unsigned w4 = packbf(p[8],  p[9]);
            unsigned w5 = packbf(p[10], p[11]);
            unsigned w6 = packbf(p[12], p[13]);
            unsigned w7 = packbf(p[14], p[15]);
            permswap(w4, w6);
            permswap(w5, w7);
            union { unsigned u[4]; bf16x8 v; } pf0, pf1;
            pf0.u[0] = w0; pf0.u[1] = w1; pf0.u[2] = w2; pf0.u[3] = w3;
            pf1.u[0] = w4; pf1.u[1] = w5; pf1.u[2] = w6; pf1.u[3] = w7;
            const int vc = sub * 32 + half * 8;
            #pragma unroll
            for (int mb = 0; mb < 2; ++mb) {
                const int vrow = mb * 32 + q5;
                const int vxor = (vrow & 7) << 4;
                bf16x8 v0 = *(const bf16x8*)(vbase + vrow * 128 + ((vc * 2) ^ vxor));
                O[mb] = __builtin_amdgcn_mfma_f32_32x32x16_bf16(v0, pf0.v, O[mb], 0, 0, 0);
                bf16x8 v1 = *(const bf16x8*)(vbase + vrow * 128 + (((vc + 16) * 2) ^ vxor));
                O[mb] = __builtin_amdgcn_mfma_f32_32x32x16_bf16(v1, pf1.v, O[mb], 0, 0, 0);
            }
        };

        #pragma unroll
        for (int sub = 0; sub < 2; ++sub)
            subtile(sub, QbA, srowA, OA, lsumA);
        if (kt <= ktmaxB) {
            #pragma unroll
            for (int sub = 0; sub < 2; ++sub)
                subtile(sub, QbB, srowB, OB, lsumB);
        }

        __syncthreads();
    }

    const float invA = 1.f / (lsumA + __shfl_xor(lsumA, 32));
    const float invB = 1.f / (lsumB + __shfl_xor(lsumB, 32));

    __bf16* crowA = ctx + (size_t)(b * T + srowA + q5) * C + h * HD;
    __bf16* crowB = ctx + (size_t)(b * T + srowB + q5) * C + h * HD;
    #pragma unroll
    for (int mb = 0; mb < 2; ++mb)
        #pragma unroll
        for (int a = 0; a < 4; ++a) {
            union { bf16x4 v; uint2 u; } pA, pB;
            #pragma unroll
            for (int bq = 0; bq < 4; ++bq) {
                pA.v[bq] = (__bf16)(OA[mb][4 * a + bq] * invA);
                pB.v[bq] = (__bf16)(OB[mb][4 * a + bq] * invB);
            }
            *(uint2*)(crowA + mb * 32 + 8 * a + 4 * half) = pA.u;
            *(uint2*)(crowB + mb * 32 + 8 * a + 4 * half) = pB.u;
        }
}

extern "C" void kernel_launch(void* const* d_in, const int* in_sizes, int n_in,
                              void* d_out, int out_size, void* d_ws, size_t ws_size,
                              hipStream_t stream) {
    constexpr int B = 4, T = 2048, C = 1024;
    constexpr int M = B * T;          // 8192
    constexpr float K1 = 0.125f * 1.44269504088896f;  // scale * log2e

    const float* x     = (const float*)d_in[0];
    const float* w_qkv = (const float*)d_in[1];
    const float* w_out = (const float*)d_in[2];
    const float* b_out = (const float*)d_in[3];
    float* out = (float*)d_out;

    char* ws = (char*)d_ws;
    __bf16* xb     = (__bf16*)(ws);                      // 16 MB
    __bf16* wqkvT  = (__bf16*)(ws + (16ull << 20));      //  6 MB
    __bf16* woutT  = (__bf16*)(ws + (22ull << 20));      //  2 MB
    __bf16* qkvb   = (__bf16*)(ws + (24ull << 20));      // 48 MB
    __bf16* ctxb   = (__bf16*)(ws + (72ull << 20));      // 16 MB
    __bf16* Vt     = (__bf16*)(ws + (88ull << 20));      // 16 MB

    // 0) casts / transposes (Q-columns of w_qkv pre-scaled by K1)
    cast_bf16<<<(M * C / 4 + 255) / 256, 256, 0, stream>>>(x, xb, M * C / 4);
    transpose_cast<<<dim3(3 * C / 32, C / 32), 256, 0, stream>>>(
        w_qkv, wqkvT, C, 3 * C, 1024, K1);
    transpose_cast<<<dim3(C / 32, C / 32), 256, 0, stream>>>(
        w_out, woutT, C, C, 0, 1.0f);

    // 1) qkv = xb @ wqkvT^T (bf16 out) + fused V-transpose into Vt
    gemm256<__bf16, false, true><<<768, 512, 0, stream>>>(
        xb, wqkvT, qkvb, nullptr, Vt, M, 3 * C, C);

    // 2) MFMA flash attention -> ctxb (r7/r8 structure, exp2-direct softmax)
    flash_attn_mfma<<<dim3(B * 16, 8), 256, 0, stream>>>(qkvb, Vt, ctxb);

    // 3) out = ctxb @ woutT^T + b_out (fp32 out) -- gemm256, 256 blocks
    gemm256<float, true, false><<<256, 512, 0, stream>>>(
        ctxb, woutT, out, b_out, nullptr, M, C, C);
}